// Round 4
// baseline (1021.509 us; speedup 1.0000x reference)
//
#include <hip/hip_runtime.h>
#include <math.h>

// GCN 2-layer forward on MI355X — dst-bucketed, LDS-accumulate edition.
// Factorization: with g = (x@W)*dinv, out[i] = dinv[i]*(sum_{in} g[src] + g[i]) + b.
// Buckets of NPB=128 consecutive dst nodes; edges partitioned per bucket (packed
// src|dstLocal<<20 in 4B); aggregation = one block per bucket, LDS float atomics.

#define NN 100000
#define NE 3200000
#define BSH 7
#define NPB 128                    // nodes per bucket = 1<<BSH
#define NB  ((NN + NPB - 1) / NPB) // 782
#define EPB 8192                   // edges per partition block

// ---------------- kernels ----------------

// deg count (global int atomics) + global bucket histogram (LDS-staged)
__global__ void k_count(const int* __restrict__ dst, int* __restrict__ deg,
                        int* __restrict__ bcnt, int E) {
    __shared__ int hist[NB];
    for (int t = threadIdx.x; t < NB; t += blockDim.x) hist[t] = 0;
    __syncthreads();
    int stride = gridDim.x * blockDim.x;
    for (int i = blockIdx.x * blockDim.x + threadIdx.x; i < E; i += stride) {
        int d = dst[i];
        atomicAdd(&deg[d], 1);
        atomicAdd(&hist[d >> BSH], 1);
    }
    __syncthreads();
    for (int t = threadIdx.x; t < NB; t += blockDim.x)
        if (hist[t]) atomicAdd(&bcnt[t], hist[t]);
}

// single-block exclusive scan of bcnt[NB] -> bbase, bcur  (NB=782 <= 1024)
__global__ void k_scanb(const int* __restrict__ bcnt, int* __restrict__ bbase,
                        int* __restrict__ bcur) {
    __shared__ int wsum[16];
    int t = threadIdx.x, lane = t & 63, w = t >> 6;
    int v = (t < NB) ? bcnt[t] : 0;
    int incl = v;
#pragma unroll
    for (int off = 1; off < 64; off <<= 1) {
        int u = __shfl_up(incl, off);
        if (lane >= off) incl += u;
    }
    if (lane == 63) wsum[w] = incl;
    __syncthreads();
    if (w == 0 && lane < 16) {
        int wv = wsum[lane];
        int winc = wv;
#pragma unroll
        for (int off = 1; off < 16; off <<= 1) {
            int u = __shfl_up(winc, off);
            if (lane >= off) winc += u;
        }
        wsum[lane] = winc - wv;
    }
    __syncthreads();
    int excl = incl - v + wsum[w];
    if (t < NB) { bbase[t] = excl; bcur[t] = excl; }
    if (t == 0) bbase[NB] = NE;
}

__global__ void k_dinv(const int* __restrict__ deg, float* __restrict__ dinv, int N) {
    int i = blockIdx.x * blockDim.x + threadIdx.x;
    if (i < N) dinv[i] = rsqrtf((float)(deg[i] + 1));  // +1 self loop
}

// g1[i,:] = (x[i,:] @ W1) * dinv[i]   (x: [N,16], W1: [16,32])
__global__ void k_gemm1(const float* __restrict__ x, const float* __restrict__ W1,
                        const float* __restrict__ dinv, float* __restrict__ g1, int N) {
    __shared__ float Ws[16 * 32];
    for (int t = threadIdx.x; t < 16 * 32; t += blockDim.x) Ws[t] = W1[t];
    __syncthreads();
    int i = blockIdx.x * blockDim.x + threadIdx.x;
    if (i >= N) return;
    const float4* xp = (const float4*)(x + (size_t)i * 16);
    float4 xa = xp[0], xb = xp[1], xc = xp[2], xd = xp[3];
    float xv[16] = {xa.x, xa.y, xa.z, xa.w, xb.x, xb.y, xb.z, xb.w,
                    xc.x, xc.y, xc.z, xc.w, xd.x, xd.y, xd.z, xd.w};
    float acc[32];
#pragma unroll
    for (int j = 0; j < 32; j++) acc[j] = 0.f;
#pragma unroll
    for (int k = 0; k < 16; k++) {
        float xk = xv[k];
#pragma unroll
        for (int j = 0; j < 32; j++) acc[j] = fmaf(xk, Ws[k * 32 + j], acc[j]);
    }
    float s = dinv[i];
    float4* gp = (float4*)(g1 + (size_t)i * 32);
#pragma unroll
    for (int q = 0; q < 8; q++) {
        float4 v;
        v.x = acc[q * 4 + 0] * s;
        v.y = acc[q * 4 + 1] * s;
        v.z = acc[q * 4 + 2] * s;
        v.w = acc[q * 4 + 3] * s;
        gp[q] = v;
    }
}

// 3-phase partition: per-block LDS hist -> reserve contiguous runs -> scatter
// packed (src | dstLocal<<20) into ebuf. Runs are contiguous => streaming writes.
__global__ void k_partition(const int* __restrict__ src, const int* __restrict__ dst,
                            int* __restrict__ bcur, unsigned int* __restrict__ ebuf,
                            int E) {
    __shared__ int hist[NB];   // counts, then block's base per bucket
    __shared__ int lcur[NB];
    int e0 = blockIdx.x * EPB;
    int e1 = min(e0 + EPB, E);
    for (int t = threadIdx.x; t < NB; t += blockDim.x) { hist[t] = 0; lcur[t] = 0; }
    __syncthreads();
    for (int e = e0 + threadIdx.x; e < e1; e += blockDim.x)
        atomicAdd(&hist[dst[e] >> BSH], 1);
    __syncthreads();
    for (int t = threadIdx.x; t < NB; t += blockDim.x) {
        int c = hist[t];
        hist[t] = c ? atomicAdd(&bcur[t], c) : 0;
    }
    __syncthreads();
    for (int e = e0 + threadIdx.x; e < e1; e += blockDim.x) {
        int d = dst[e];
        int b = d >> BSH;
        int pos = hist[b] + atomicAdd(&lcur[b], 1);
        ebuf[pos] = (unsigned)src[e] | ((unsigned)(d & (NPB - 1)) << 20);
    }
}

// Layer-1: one block per bucket. LDS acc[128][33] (stride 33 breaks bank
// conflicts). 8 lanes/edge, float4 gather of g1[src], ds_add_f32 accumulate.
// Epilogue: + self, relu(dinv*sum+b1), @W2, *dinv -> g2.
__global__ void __launch_bounds__(256) k_l1b(
        const int* __restrict__ bbase, const unsigned int* __restrict__ ebuf,
        const float* __restrict__ g1, const float* __restrict__ dinv,
        const float* __restrict__ b1, const float* __restrict__ W2,
        float* __restrict__ g2, int N) {
    __shared__ float acc[NPB * 33];
    __shared__ float W2s[96];
    __shared__ float b1s[32];
    for (int t = threadIdx.x; t < NPB * 33; t += 256) acc[t] = 0.f;
    if (threadIdx.x < 96) W2s[threadIdx.x] = W2[threadIdx.x];
    if (threadIdx.x < 32) b1s[threadIdx.x] = b1[threadIdx.x];
    __syncthreads();
    int b = blockIdx.x;
    int beg = bbase[b], end = bbase[b + 1];
    int f4 = (threadIdx.x & 7) * 4;
    for (int j = beg + (threadIdx.x >> 3); j < end; j += 32) {
        unsigned pe = ebuf[j];
        int s  = pe & 0xFFFFF;
        int dl = pe >> 20;
        float4 v = *(const float4*)(g1 + (size_t)s * 32 + f4);
        float* a = acc + dl * 33 + f4;
        atomicAdd(a + 0, v.x);
        atomicAdd(a + 1, v.y);
        atomicAdd(a + 2, v.z);
        atomicAdd(a + 3, v.w);
    }
    __syncthreads();
    int node0 = b << BSH;
    int nloc = min(NPB, N - node0);
    for (int nl = threadIdx.x; nl < nloc; nl += 256) {
        int i = node0 + nl;
        float di = dinv[i];
        const float* gs = g1 + (size_t)i * 32;
        float o0 = 0.f, o1 = 0.f, o2 = 0.f;
#pragma unroll
        for (int f = 0; f < 32; f++) {
            float z = fmaf(di, acc[nl * 33 + f] + gs[f], b1s[f]);
            z = fmaxf(z, 0.f);
            o0 = fmaf(z, W2s[f * 3 + 0], o0);
            o1 = fmaf(z, W2s[f * 3 + 1], o1);
            o2 = fmaf(z, W2s[f * 3 + 2], o2);
        }
        g2[(size_t)i * 3 + 0] = o0 * di;
        g2[(size_t)i * 3 + 1] = o1 * di;
        g2[(size_t)i * 3 + 2] = o2 * di;
    }
}

// Layer-2: one block per bucket. LDS acc[128][5] (stride 5). Thread/edge,
// 3 ds_add_f32. Epilogue: + self, +b2, log_softmax -> out.
__global__ void __launch_bounds__(256) k_l2b(
        const int* __restrict__ bbase, const unsigned int* __restrict__ ebuf,
        const float* __restrict__ g2, const float* __restrict__ dinv,
        const float* __restrict__ b2, float* __restrict__ out, int N) {
    __shared__ float acc[NPB * 5];
    __shared__ float b2s[3];
    for (int t = threadIdx.x; t < NPB * 5; t += 256) acc[t] = 0.f;
    if (threadIdx.x < 3) b2s[threadIdx.x] = b2[threadIdx.x];
    __syncthreads();
    int b = blockIdx.x;
    int beg = bbase[b], end = bbase[b + 1];
    for (int j = beg + threadIdx.x; j < end; j += 256) {
        unsigned pe = ebuf[j];
        int s  = pe & 0xFFFFF;
        int dl = pe >> 20;
        const float* gp = g2 + (size_t)s * 3;
        float v0 = gp[0], v1 = gp[1], v2 = gp[2];
        float* a = acc + dl * 5;
        atomicAdd(a + 0, v0);
        atomicAdd(a + 1, v1);
        atomicAdd(a + 2, v2);
    }
    __syncthreads();
    int node0 = b << BSH;
    int nloc = min(NPB, N - node0);
    for (int nl = threadIdx.x; nl < nloc; nl += 256) {
        int i = node0 + nl;
        float di = dinv[i];
        float v0 = fmaf(di, acc[nl * 5 + 0] + g2[(size_t)i * 3 + 0], b2s[0]);
        float v1 = fmaf(di, acc[nl * 5 + 1] + g2[(size_t)i * 3 + 1], b2s[1]);
        float v2 = fmaf(di, acc[nl * 5 + 2] + g2[(size_t)i * 3 + 2], b2s[2]);
        float m = fmaxf(v0, fmaxf(v1, v2));
        float lse = m + logf(expf(v0 - m) + expf(v1 - m) + expf(v2 - m));
        out[(size_t)i * 3 + 0] = v0 - lse;
        out[(size_t)i * 3 + 1] = v1 - lse;
        out[(size_t)i * 3 + 2] = v2 - lse;
    }
}

// ---------------- launch ----------------

extern "C" void kernel_launch(void* const* d_in, const int* in_sizes, int n_in,
                              void* d_out, int out_size, void* d_ws, size_t ws_size,
                              hipStream_t stream) {
    const float* x  = (const float*)d_in[0];
    const int*   ei = (const int*)d_in[1];   // [2, E] int32
    const float* W1 = (const float*)d_in[2];
    const float* b1 = (const float*)d_in[3];
    const float* W2 = (const float*)d_in[4];
    const float* b2 = (const float*)d_in[5];
    float* out = (float*)d_out;

    const int* src = ei;
    const int* dst = ei + NE;

    // ws (4B units): ebuf[NE] | g1[N*32] | g2[N*3] | deg[N] | dinv[N]
    //              | bcnt[NB] | bbase[NB+1] | bcur[NB]     (~28 MB)
    unsigned int* ebuf = (unsigned int*)d_ws;
    float* g1   = (float*)(ebuf + (size_t)NE);
    float* g2   = g1 + (size_t)NN * 32;
    int*   deg  = (int*)(g2 + (size_t)NN * 3);
    float* dinv = (float*)(deg + NN);
    int*   bcnt = (int*)(dinv + NN);
    int*   bbase= bcnt + NB;
    int*   bcur = bbase + NB + 1;

    (void)hipMemsetAsync(deg,  0, (size_t)NN * 4, stream);
    (void)hipMemsetAsync(bcnt, 0, (size_t)NB * 4, stream);

    const int B = 256;
    int gbN = (NN + B - 1) / B;
    int gbP = (NE + EPB - 1) / EPB;

    k_count<<<512, B, 0, stream>>>(dst, deg, bcnt, NE);
    k_scanb<<<1, 1024, 0, stream>>>(bcnt, bbase, bcur);
    k_dinv<<<gbN, B, 0, stream>>>(deg, dinv, NN);
    k_gemm1<<<gbN, B, 0, stream>>>(x, W1, dinv, g1, NN);
    k_partition<<<gbP, B, 0, stream>>>(src, dst, bcur, ebuf, NE);
    k_l1b<<<NB, B, 0, stream>>>(bbase, ebuf, g1, dinv, b1, W2, g2, NN);
    k_l2b<<<NB, B, 0, stream>>>(bbase, ebuf, g2, dinv, b2, out, NN);
}

// Round 5
// 329.635 us; speedup vs baseline: 3.0989x; 3.0989x over previous
//
#include <hip/hip_runtime.h>
#include <math.h>

// GCN 2-layer forward on MI355X — CSR via bucketed counting sort, atomic-free aggregation.
// Linearity trick: sum_{in} g1[src] = (sum_{in} x[src]*dinv[src]) @ W1, so layer-1
// aggregates 16-dim xs rows (64B) and applies W1/relu/W2 per node in-wave.
//
// count(bucket hist) -> scanb -> partition(contiguous runs) -> csr(per-bucket
// counting sort => col,rowptr,dinv) -> scale(xs=x*dinv) -> l1(wave/node) -> l2(wave/node)

#define NN 100000
#define NE 3200000
#define BSH 7
#define NPB 128                     // nodes per bucket
#define NB  ((NN + NPB - 1) / NPB)  // 782
#define EPB 16384                   // edges per partition block

// ---------------- kernels ----------------

// bucket histogram only (no global per-node atomics)
__global__ void k_count(const int* __restrict__ dst, int* __restrict__ bcnt, int E) {
    __shared__ int hist[NB];
    for (int t = threadIdx.x; t < NB; t += blockDim.x) hist[t] = 0;
    __syncthreads();
    int stride = gridDim.x * blockDim.x;
    for (int i = blockIdx.x * blockDim.x + threadIdx.x; i < E; i += stride)
        atomicAdd(&hist[dst[i] >> BSH], 1);
    __syncthreads();
    for (int t = threadIdx.x; t < NB; t += blockDim.x)
        if (hist[t]) atomicAdd(&bcnt[t], hist[t]);
}

// single-block exclusive scan of bcnt[NB] -> bbase, bcur
__global__ void k_scanb(const int* __restrict__ bcnt, int* __restrict__ bbase,
                        int* __restrict__ bcur) {
    __shared__ int wsum[16];
    int t = threadIdx.x, lane = t & 63, w = t >> 6;
    int v = (t < NB) ? bcnt[t] : 0;
    int incl = v;
#pragma unroll
    for (int off = 1; off < 64; off <<= 1) {
        int u = __shfl_up(incl, off);
        if (lane >= off) incl += u;
    }
    if (lane == 63) wsum[w] = incl;
    __syncthreads();
    if (w == 0 && lane < 16) {
        int wv = wsum[lane];
        int winc = wv;
#pragma unroll
        for (int off = 1; off < 16; off <<= 1) {
            int u = __shfl_up(winc, off);
            if (lane >= off) winc += u;
        }
        wsum[lane] = winc - wv;
    }
    __syncthreads();
    int excl = incl - v + wsum[w];
    if (t < NB) { bbase[t] = excl; bcur[t] = excl; }
    if (t == 0) bbase[NB] = NE;
}

// 3-phase partition: LDS hist -> reserve contiguous runs -> scatter packed
// (src | dstLocal<<20). Runs ~21 edges => near-line-granular writes.
__global__ void __launch_bounds__(256) k_partition(
        const int* __restrict__ src, const int* __restrict__ dst,
        int* __restrict__ bcur, unsigned int* __restrict__ ebuf, int E) {
    __shared__ int hist[NB];
    __shared__ int lcur[NB];
    int e0 = blockIdx.x * EPB;
    int e1 = min(e0 + EPB, E);
    for (int t = threadIdx.x; t < NB; t += 256) { hist[t] = 0; lcur[t] = 0; }
    __syncthreads();
    for (int e = e0 + threadIdx.x; e < e1; e += 256)
        atomicAdd(&hist[dst[e] >> BSH], 1);
    __syncthreads();
    for (int t = threadIdx.x; t < NB; t += 256) {
        int c = hist[t];
        hist[t] = c ? atomicAdd(&bcur[t], c) : 0;
    }
    __syncthreads();
    for (int e = e0 + threadIdx.x; e < e1; e += 256) {
        int d = dst[e];
        int b = d >> BSH;
        int pos = hist[b] + atomicAdd(&lcur[b], 1);
        ebuf[pos] = (unsigned)src[e] | ((unsigned)(d & (NPB - 1)) << 20);
    }
}

// per-bucket counting sort by dstLocal: builds col (node-sorted src), rowptr, dinv.
__global__ void __launch_bounds__(256) k_csr(
        const int* __restrict__ bbase, const unsigned int* __restrict__ ebuf,
        int* __restrict__ col, int* __restrict__ rowptr, float* __restrict__ dinv,
        int N) {
    __shared__ int hist[NPB];
    __shared__ int base[NPB];
    __shared__ int lcur[NPB];
    __shared__ int wtot;
    int b = blockIdx.x;
    int tid = threadIdx.x;
    int beg = bbase[b], end = bbase[b + 1];
    if (tid < NPB) { hist[tid] = 0; lcur[tid] = 0; }
    __syncthreads();
    for (int j = beg + tid; j < end; j += 256)
        atomicAdd(&hist[ebuf[j] >> 20], 1);
    __syncthreads();
    int lane = tid & 63, w = tid >> 6;
    int v = (tid < NPB) ? hist[tid] : 0;
    int incl = v;
#pragma unroll
    for (int off = 1; off < 64; off <<= 1) {
        int u = __shfl_up(incl, off);
        if (lane >= off) incl += u;
    }
    if (tid == 63) wtot = incl;   // wave-0 total
    __syncthreads();
    int excl = incl - v + ((w == 1) ? wtot : 0);
    int node0 = b << BSH;
    if (tid < NPB) {
        base[tid] = excl;
        int node = node0 + tid;
        if (node < N) {
            rowptr[node] = beg + excl;
            dinv[node] = rsqrtf((float)(v + 1));  // +1 self loop
        }
    }
    if (b == NB - 1 && tid == 0) rowptr[N] = NE;
    __syncthreads();
    for (int j = beg + tid; j < end; j += 256) {
        unsigned pe = ebuf[j];
        int dl = pe >> 20;
        int pos = beg + base[dl] + atomicAdd(&lcur[dl], 1);
        col[pos] = (int)(pe & 0xFFFFF);
    }
}

// xs[i,f] = x[i,f] * dinv[i]  (float4 over N*4 vectors)
__global__ void k_scale(const float* __restrict__ x, const float* __restrict__ dinv,
                        float* __restrict__ xs, int N4) {
    int i4 = blockIdx.x * blockDim.x + threadIdx.x;
    if (i4 >= N4) return;
    float di = dinv[i4 >> 2];
    float4 v = ((const float4*)x)[i4];
    v.x *= di; v.y *= di; v.z *= di; v.w *= di;
    ((float4*)xs)[i4] = v;
}

// Layer-1 fused: one wave per node. Quarter-wave per edge (16 feature lanes,
// 64B coalesced xs row). agg16 -> @W1 (+b1, relu) -> @W2 -> *dinv -> g2[3].
__global__ void __launch_bounds__(256) k_l1(
        const int* __restrict__ rowptr, const int* __restrict__ col,
        const float* __restrict__ xs, const float* __restrict__ dinv,
        const float* __restrict__ W1, const float* __restrict__ b1,
        const float* __restrict__ W2, float* __restrict__ g2, int N) {
    __shared__ float W1s[16 * 32];
    __shared__ float W2s[96];
    __shared__ float b1s[32];
    for (int t = threadIdx.x; t < 512; t += 256) W1s[t] = W1[t];
    if (threadIdx.x < 96) W2s[threadIdx.x] = W2[threadIdx.x];
    if (threadIdx.x < 32) b1s[threadIdx.x] = b1[threadIdx.x];
    __syncthreads();
    int wid = (int)((blockIdx.x * 256 + threadIdx.x) >> 6);
    if (wid >= N) return;  // wave-uniform
    int lane = threadIdx.x & 63;
    int q = lane >> 4, f = lane & 15;
    int beg = rowptr[wid], end = rowptr[wid + 1];
    float acc = 0.f;
    for (int j = beg + q; j < end; j += 4) {
        int s = col[j];
        acc += xs[(size_t)s * 16 + f];
    }
    acc += __shfl_down(acc, 32);
    acc += __shfl_down(acc, 16);           // lanes 0..15 hold agg16[f]
    acc += (q == 0) ? xs[(size_t)wid * 16 + f] : 0.f;  // self term (lanes 0..15)
    float di = dinv[wid];
    // h[j] for j = 2f, 2f+1 : broadcast agg features via shfl
    float o0 = 0.f, o1 = 0.f;
#pragma unroll
    for (int k = 0; k < 16; k++) {
        float a = __shfl(acc, k);
        o0 = fmaf(a, W1s[k * 32 + 2 * f + 0], o0);
        o1 = fmaf(a, W1s[k * 32 + 2 * f + 1], o1);
    }
    float z0 = fmaxf(fmaf(di, o0, b1s[2 * f + 0]), 0.f);
    float z1 = fmaxf(fmaf(di, o1, b1s[2 * f + 1]), 0.f);
    float p0 = fmaf(z0, W2s[(2 * f) * 3 + 0], z1 * W2s[(2 * f + 1) * 3 + 0]);
    float p1 = fmaf(z0, W2s[(2 * f) * 3 + 1], z1 * W2s[(2 * f + 1) * 3 + 1]);
    float p2 = fmaf(z0, W2s[(2 * f) * 3 + 2], z1 * W2s[(2 * f + 1) * 3 + 2]);
#pragma unroll
    for (int off = 8; off >= 1; off >>= 1) {   // sums lanes 0..15 into lane 0
        p0 += __shfl_down(p0, off);
        p1 += __shfl_down(p1, off);
        p2 += __shfl_down(p2, off);
    }
    if (lane == 0) {
        g2[(size_t)wid * 3 + 0] = p0 * di;
        g2[(size_t)wid * 3 + 1] = p1 * di;
        g2[(size_t)wid * 3 + 2] = p2 * di;
    }
}

// Layer-2 fused: one wave per node, lanes stride edges, 3 accs, shuffle reduce,
// + self + bias, log_softmax.
__global__ void __launch_bounds__(256) k_l2(
        const int* __restrict__ rowptr, const int* __restrict__ col,
        const float* __restrict__ g2, const float* __restrict__ dinv,
        const float* __restrict__ b2, float* __restrict__ out, int N) {
    int wid = (int)((blockIdx.x * 256 + threadIdx.x) >> 6);
    if (wid >= N) return;
    int lane = threadIdx.x & 63;
    int beg = rowptr[wid], end = rowptr[wid + 1];
    float a0 = 0.f, a1 = 0.f, a2 = 0.f;
    for (int j = beg + lane; j < end; j += 64) {
        int s = col[j];
        const float* gp = g2 + (size_t)s * 3;
        a0 += gp[0]; a1 += gp[1]; a2 += gp[2];
    }
#pragma unroll
    for (int off = 32; off >= 1; off >>= 1) {
        a0 += __shfl_down(a0, off);
        a1 += __shfl_down(a1, off);
        a2 += __shfl_down(a2, off);
    }
    if (lane == 0) {
        float di = dinv[wid];
        float v0 = fmaf(di, a0 + g2[(size_t)wid * 3 + 0], b2[0]);
        float v1 = fmaf(di, a1 + g2[(size_t)wid * 3 + 1], b2[1]);
        float v2 = fmaf(di, a2 + g2[(size_t)wid * 3 + 2], b2[2]);
        float m = fmaxf(v0, fmaxf(v1, v2));
        float lse = m + logf(expf(v0 - m) + expf(v1 - m) + expf(v2 - m));
        out[(size_t)wid * 3 + 0] = v0 - lse;
        out[(size_t)wid * 3 + 1] = v1 - lse;
        out[(size_t)wid * 3 + 2] = v2 - lse;
    }
}

// ---------------- launch ----------------

extern "C" void kernel_launch(void* const* d_in, const int* in_sizes, int n_in,
                              void* d_out, int out_size, void* d_ws, size_t ws_size,
                              hipStream_t stream) {
    const float* x  = (const float*)d_in[0];
    const int*   ei = (const int*)d_in[1];   // [2, E] int32
    const float* W1 = (const float*)d_in[2];
    const float* b1 = (const float*)d_in[3];
    const float* W2 = (const float*)d_in[4];
    const float* b2 = (const float*)d_in[5];
    float* out = (float*)d_out;

    const int* src = ei;
    const int* dst = ei + NE;

    // ws (4B units): ebuf[NE] (xs[N*16] aliases its head after k_csr consumes it)
    //              | col[NE] | g2[N*3] | dinv[N] | rowptr[N+1] | bcnt | bbase | bcur
    unsigned int* ebuf = (unsigned int*)d_ws;
    float* xs   = (float*)d_ws;              // alias: ebuf dead after k_csr
    int*   col  = (int*)(ebuf + (size_t)NE);
    float* g2   = (float*)(col + (size_t)NE);
    float* dinv = g2 + (size_t)NN * 3;
    int*   rowptr = (int*)(dinv + NN);
    int*   bcnt = rowptr + NN + 1;
    int*   bbase = bcnt + NB;
    int*   bcur  = bbase + NB + 1;

    (void)hipMemsetAsync(bcnt, 0, (size_t)NB * 4, stream);

    const int B = 256;
    int gbP = (NE + EPB - 1) / EPB;
    int gbS = (NN * 4 + B - 1) / B;
    int gbW = (NN * 64 + B - 1) / B;  // one wave per node

    k_count<<<512, B, 0, stream>>>(dst, bcnt, NE);
    k_scanb<<<1, 1024, 0, stream>>>(bcnt, bbase, bcur);
    k_partition<<<gbP, B, 0, stream>>>(src, dst, bcur, ebuf, NE);
    k_csr<<<NB, B, 0, stream>>>(bbase, ebuf, col, rowptr, dinv, NN);
    k_scale<<<gbS, B, 0, stream>>>(x, dinv, xs, NN * 4);
    k_l1<<<gbW, B, 0, stream>>>(rowptr, col, xs, dinv, W1, b1, W2, g2, NN);
    k_l2<<<gbW, B, 0, stream>>>(rowptr, col, g2, dinv, b2, out, NN);
}

// Round 6
// 311.364 us; speedup vs baseline: 3.2808x; 1.0587x over previous
//
#include <hip/hip_runtime.h>
#include <math.h>

// GCN 2-layer forward on MI355X — CSR via bucketed counting sort, atomic-free aggregation.
// Linearity trick: sum_{in} g1[src] = (sum_{in} x[src]*dinv[src]) @ W1, so layer-1
// aggregates 16-dim xs rows (64B, float4 per lane) and applies W1/relu/W2 in-wave.

#define NN 100000
#define NE 3200000
#define BSH 7
#define NPB 128                     // nodes per bucket
#define NB  ((NN + NPB - 1) / NPB)  // 782
#define EPB 4096                    // edges per partition block (782 blocks ~ 3/CU)

// ---------------- kernels ----------------

// bucket histogram only
__global__ void k_count(const int* __restrict__ dst, int* __restrict__ bcnt, int E) {
    __shared__ int hist[NB];
    for (int t = threadIdx.x; t < NB; t += blockDim.x) hist[t] = 0;
    __syncthreads();
    int stride = gridDim.x * blockDim.x;
    for (int i = blockIdx.x * blockDim.x + threadIdx.x; i < E; i += stride)
        atomicAdd(&hist[dst[i] >> BSH], 1);
    __syncthreads();
    for (int t = threadIdx.x; t < NB; t += blockDim.x)
        if (hist[t]) atomicAdd(&bcnt[t], hist[t]);
}

// single-block exclusive scan of bcnt[NB] -> bbase, bcur
__global__ void k_scanb(const int* __restrict__ bcnt, int* __restrict__ bbase,
                        int* __restrict__ bcur) {
    __shared__ int wsum[16];
    int t = threadIdx.x, lane = t & 63, w = t >> 6;
    int v = (t < NB) ? bcnt[t] : 0;
    int incl = v;
#pragma unroll
    for (int off = 1; off < 64; off <<= 1) {
        int u = __shfl_up(incl, off);
        if (lane >= off) incl += u;
    }
    if (lane == 63) wsum[w] = incl;
    __syncthreads();
    if (w == 0 && lane < 16) {
        int wv = wsum[lane];
        int winc = wv;
#pragma unroll
        for (int off = 1; off < 16; off <<= 1) {
            int u = __shfl_up(winc, off);
            if (lane >= off) winc += u;
        }
        wsum[lane] = winc - wv;
    }
    __syncthreads();
    int excl = incl - v + wsum[w];
    if (t < NB) { bbase[t] = excl; bcur[t] = excl; }
    if (t == 0) bbase[NB] = NE;
}

// 3-phase partition: LDS hist -> reserve contiguous runs -> scatter packed
// (src | dstLocal<<20).
__global__ void __launch_bounds__(256) k_partition(
        const int* __restrict__ src, const int* __restrict__ dst,
        int* __restrict__ bcur, unsigned int* __restrict__ ebuf, int E) {
    __shared__ int hist[NB];
    __shared__ int lcur[NB];
    int e0 = blockIdx.x * EPB;
    int e1 = min(e0 + EPB, E);
    for (int t = threadIdx.x; t < NB; t += 256) { hist[t] = 0; lcur[t] = 0; }
    __syncthreads();
    for (int e = e0 + threadIdx.x; e < e1; e += 256)
        atomicAdd(&hist[dst[e] >> BSH], 1);
    __syncthreads();
    for (int t = threadIdx.x; t < NB; t += 256) {
        int c = hist[t];
        hist[t] = c ? atomicAdd(&bcur[t], c) : 0;
    }
    __syncthreads();
    for (int e = e0 + threadIdx.x; e < e1; e += 256) {
        int d = dst[e];
        int b = d >> BSH;
        int pos = hist[b] + atomicAdd(&lcur[b], 1);
        ebuf[pos] = (unsigned)src[e] | ((unsigned)(d & (NPB - 1)) << 20);
    }
}

// per-bucket counting sort by dstLocal: builds col (node-sorted src), rowptr, dinv.
__global__ void __launch_bounds__(256) k_csr(
        const int* __restrict__ bbase, const unsigned int* __restrict__ ebuf,
        int* __restrict__ col, int* __restrict__ rowptr, float* __restrict__ dinv,
        int N) {
    __shared__ int hist[NPB];
    __shared__ int base[NPB];
    __shared__ int lcur[NPB];
    __shared__ int wtot;
    int b = blockIdx.x;
    int tid = threadIdx.x;
    int beg = bbase[b], end = bbase[b + 1];
    if (tid < NPB) { hist[tid] = 0; lcur[tid] = 0; }
    __syncthreads();
    for (int j = beg + tid; j < end; j += 256)
        atomicAdd(&hist[ebuf[j] >> 20], 1);
    __syncthreads();
    int lane = tid & 63, w = tid >> 6;
    int v = (tid < NPB) ? hist[tid] : 0;
    int incl = v;
#pragma unroll
    for (int off = 1; off < 64; off <<= 1) {
        int u = __shfl_up(incl, off);
        if (lane >= off) incl += u;
    }
    if (tid == 63) wtot = incl;
    __syncthreads();
    int excl = incl - v + ((w == 1) ? wtot : 0);
    int node0 = b << BSH;
    if (tid < NPB) {
        base[tid] = excl;
        int node = node0 + tid;
        if (node < N) {
            rowptr[node] = beg + excl;
            dinv[node] = rsqrtf((float)(v + 1));  // +1 self loop
        }
    }
    if (b == NB - 1 && tid == 0) rowptr[N] = NE;
    __syncthreads();
    for (int j = beg + tid; j < end; j += 256) {
        unsigned pe = ebuf[j];
        int dl = pe >> 20;
        int pos = beg + base[dl] + atomicAdd(&lcur[dl], 1);
        col[pos] = (int)(pe & 0xFFFFF);
    }
}

// xs[i,f] = x[i,f] * dinv[i]
__global__ void k_scale(const float* __restrict__ x, const float* __restrict__ dinv,
                        float* __restrict__ xs, int N4) {
    int i4 = blockIdx.x * blockDim.x + threadIdx.x;
    if (i4 >= N4) return;
    float di = dinv[i4 >> 2];
    float4 v = ((const float4*)x)[i4];
    v.x *= di; v.y *= di; v.z *= di; v.w *= di;
    ((float4*)xs)[i4] = v;
}

// Layer-1 fused: one wave per node. 4 lanes/edge, float4 gather (16 edges per
// wave-instruction). agg16 -> @W1 (+b1, relu) -> @W2 -> *dinv -> g2[4] (padded).
__global__ void __launch_bounds__(256) k_l1(
        const int* __restrict__ rowptr, const int* __restrict__ col,
        const float* __restrict__ xs, const float* __restrict__ dinv,
        const float* __restrict__ W1, const float* __restrict__ b1,
        const float* __restrict__ W2, float* __restrict__ g2, int N) {
    __shared__ float W1s[16 * 32];
    __shared__ float W2s[96];
    __shared__ float b1s[32];
    for (int t = threadIdx.x; t < 512; t += 256) W1s[t] = W1[t];
    if (threadIdx.x < 96) W2s[threadIdx.x] = W2[threadIdx.x];
    if (threadIdx.x < 32) b1s[threadIdx.x] = b1[threadIdx.x];
    __syncthreads();
    int wid = (int)((blockIdx.x * 256 + threadIdx.x) >> 6);
    if (wid >= N) return;  // wave-uniform
    int lane = threadIdx.x & 63;
    int r = lane >> 2, c = lane & 3;  // edge slot 0..15, float4 chunk 0..3
    int beg = rowptr[wid], end = rowptr[wid + 1];
    const float4* xs4 = (const float4*)xs;
    float4 a4 = make_float4(0.f, 0.f, 0.f, 0.f);
    for (int j = beg + r; j < end; j += 16) {
        int s = col[j];
        float4 v = xs4[(size_t)s * 4 + c];
        a4.x += v.x; a4.y += v.y; a4.z += v.z; a4.w += v.w;
    }
    // fold 16 edge slots -> lanes 0..3 (per-component shfl)
#pragma unroll
    for (int off = 32; off >= 4; off >>= 1) {
        a4.x += __shfl_down(a4.x, off);
        a4.y += __shfl_down(a4.y, off);
        a4.z += __shfl_down(a4.z, off);
        a4.w += __shfl_down(a4.w, off);
    }
    if (lane < 4) {  // self term
        float4 v = xs4[(size_t)wid * 4 + lane];
        a4.x += v.x; a4.y += v.y; a4.z += v.z; a4.w += v.w;
    }
    float di = dinv[wid];
    // broadcast agg[0..15]: feature k lives in component (k&3) of lane (k>>2)
    float o0 = 0.f, o1 = 0.f;
    int f = lane & 15;
#pragma unroll
    for (int k = 0; k < 16; k++) {
        float comp = (k & 3) == 0 ? a4.x : (k & 3) == 1 ? a4.y : (k & 3) == 2 ? a4.z : a4.w;
        float a = __shfl(comp, k >> 2);
        o0 = fmaf(a, W1s[k * 32 + 2 * f + 0], o0);
        o1 = fmaf(a, W1s[k * 32 + 2 * f + 1], o1);
    }
    float z0 = fmaxf(fmaf(di, o0, b1s[2 * f + 0]), 0.f);
    float z1 = fmaxf(fmaf(di, o1, b1s[2 * f + 1]), 0.f);
    float p0 = fmaf(z0, W2s[(2 * f) * 3 + 0], z1 * W2s[(2 * f + 1) * 3 + 0]);
    float p1 = fmaf(z0, W2s[(2 * f) * 3 + 1], z1 * W2s[(2 * f + 1) * 3 + 1]);
    float p2 = fmaf(z0, W2s[(2 * f) * 3 + 2], z1 * W2s[(2 * f + 1) * 3 + 2]);
#pragma unroll
    for (int off = 8; off >= 1; off >>= 1) {  // sum lanes 0..15 into lane 0
        p0 += __shfl_down(p0, off);
        p1 += __shfl_down(p1, off);
        p2 += __shfl_down(p2, off);
    }
    if (lane == 0) {
        float4 o;
        o.x = p0 * di; o.y = p1 * di; o.z = p2 * di; o.w = 0.f;
        ((float4*)g2)[wid] = o;   // padded stride-4 row
    }
}

// Layer-2 fused: one wave per node, lane/edge, float4 g2 gather, shuffle reduce,
// + self + bias, log_softmax.
__global__ void __launch_bounds__(256) k_l2(
        const int* __restrict__ rowptr, const int* __restrict__ col,
        const float* __restrict__ g2, const float* __restrict__ dinv,
        const float* __restrict__ b2, float* __restrict__ out, int N) {
    int wid = (int)((blockIdx.x * 256 + threadIdx.x) >> 6);
    if (wid >= N) return;
    int lane = threadIdx.x & 63;
    int beg = rowptr[wid], end = rowptr[wid + 1];
    const float4* g24 = (const float4*)g2;
    float a0 = 0.f, a1 = 0.f, a2 = 0.f;
    for (int j = beg + lane; j < end; j += 64) {
        float4 v = g24[col[j]];
        a0 += v.x; a1 += v.y; a2 += v.z;
    }
#pragma unroll
    for (int off = 32; off >= 1; off >>= 1) {
        a0 += __shfl_down(a0, off);
        a1 += __shfl_down(a1, off);
        a2 += __shfl_down(a2, off);
    }
    if (lane == 0) {
        float di = dinv[wid];
        float4 self = g24[wid];
        float v0 = fmaf(di, a0 + self.x, b2[0]);
        float v1 = fmaf(di, a1 + self.y, b2[1]);
        float v2 = fmaf(di, a2 + self.z, b2[2]);
        float m = fmaxf(v0, fmaxf(v1, v2));
        float lse = m + logf(expf(v0 - m) + expf(v1 - m) + expf(v2 - m));
        out[(size_t)wid * 3 + 0] = v0 - lse;
        out[(size_t)wid * 3 + 1] = v1 - lse;
        out[(size_t)wid * 3 + 2] = v2 - lse;
    }
}

// ---------------- launch ----------------

extern "C" void kernel_launch(void* const* d_in, const int* in_sizes, int n_in,
                              void* d_out, int out_size, void* d_ws, size_t ws_size,
                              hipStream_t stream) {
    const float* x  = (const float*)d_in[0];
    const int*   ei = (const int*)d_in[1];   // [2, E] int32
    const float* W1 = (const float*)d_in[2];
    const float* b1 = (const float*)d_in[3];
    const float* W2 = (const float*)d_in[4];
    const float* b2 = (const float*)d_in[5];
    float* out = (float*)d_out;

    const int* src = ei;
    const int* dst = ei + NE;

    // ws (4B units): ebuf[NE] (xs[N*16] aliases it after k_csr)
    //              | col[NE] | g2[N*4] | dinv[N] | rowptr[N+1] | bcnt | bbase | bcur
    unsigned int* ebuf = (unsigned int*)d_ws;
    float* xs   = (float*)d_ws;              // alias: ebuf dead after k_csr
    int*   col  = (int*)(ebuf + (size_t)NE);
    float* g2   = (float*)(col + (size_t)NE);
    float* dinv = g2 + (size_t)NN * 4;
    int*   rowptr = (int*)(dinv + NN);
    int*   bcnt = rowptr + NN + 1;
    int*   bbase = bcnt + NB;
    int*   bcur  = bbase + NB + 1;

    (void)hipMemsetAsync(bcnt, 0, (size_t)NB * 4, stream);

    const int B = 256;
    int gbP = (NE + EPB - 1) / EPB;
    int gbS = (NN * 4 + B - 1) / B;
    int gbW = (NN * 64 + B - 1) / B;  // one wave per node

    k_count<<<512, B, 0, stream>>>(dst, bcnt, NE);
    k_scanb<<<1, 1024, 0, stream>>>(bcnt, bbase, bcur);
    k_partition<<<gbP, B, 0, stream>>>(src, dst, bcur, ebuf, NE);
    k_csr<<<NB, B, 0, stream>>>(bbase, ebuf, col, rowptr, dinv, NN);
    k_scale<<<gbS, B, 0, stream>>>(x, dinv, xs, NN * 4);
    k_l1<<<gbW, B, 0, stream>>>(rowptr, col, xs, dinv, W1, b1, W2, g2, NN);
    k_l2<<<gbW, B, 0, stream>>>(rowptr, col, g2, dinv, b2, out, NN);
}

// Round 7
// 273.112 us; speedup vs baseline: 3.7403x; 1.1401x over previous
//
#include <hip/hip_runtime.h>
#include <math.h>

// GCN 2-layer forward on MI355X — CSR via bucketed counting sort, atomic-free aggregation.
// Linearity trick: sum_{in} g1[src] = (sum_{in} x[src]*dinv[src]) @ W1, so layer-1
// aggregates 16-dim xs rows (64B, float4 per lane) and applies W1/relu/W2 in-wave.

#define NN 100000
#define NE 3200000
#define BSH 8
#define NPB 256                     // nodes per bucket
#define NB  ((NN + NPB - 1) / NPB)  // 391
#define EPB 8192                    // edges per partition block (391 blocks)

// ---------------- kernels ----------------

// bucket histogram only (int4 edge reads)
__global__ void k_count(const int4* __restrict__ dst4, int* __restrict__ bcnt, int E4) {
    __shared__ int hist[NB];
    for (int t = threadIdx.x; t < NB; t += blockDim.x) hist[t] = 0;
    __syncthreads();
    int stride = gridDim.x * blockDim.x;
    for (int i = blockIdx.x * blockDim.x + threadIdx.x; i < E4; i += stride) {
        int4 d = dst4[i];
        atomicAdd(&hist[d.x >> BSH], 1);
        atomicAdd(&hist[d.y >> BSH], 1);
        atomicAdd(&hist[d.z >> BSH], 1);
        atomicAdd(&hist[d.w >> BSH], 1);
    }
    __syncthreads();
    for (int t = threadIdx.x; t < NB; t += blockDim.x)
        if (hist[t]) atomicAdd(&bcnt[t], hist[t]);
}

// single-block exclusive scan of bcnt[NB] -> bbase, bcur  (NB=391 <= 1024)
__global__ void k_scanb(const int* __restrict__ bcnt, int* __restrict__ bbase,
                        int* __restrict__ bcur) {
    __shared__ int wsum[16];
    int t = threadIdx.x, lane = t & 63, w = t >> 6;
    int v = (t < NB) ? bcnt[t] : 0;
    int incl = v;
#pragma unroll
    for (int off = 1; off < 64; off <<= 1) {
        int u = __shfl_up(incl, off);
        if (lane >= off) incl += u;
    }
    if (lane == 63) wsum[w] = incl;
    __syncthreads();
    if (w == 0 && lane < 16) {
        int wv = wsum[lane];
        int winc = wv;
#pragma unroll
        for (int off = 1; off < 16; off <<= 1) {
            int u = __shfl_up(winc, off);
            if (lane >= off) winc += u;
        }
        wsum[lane] = winc - wv;
    }
    __syncthreads();
    int excl = incl - v + wsum[w];
    if (t < NB) { bbase[t] = excl; bcur[t] = excl; }
    if (t == 0) bbase[NB] = NE;
}

// 3-phase partition: LDS hist -> reserve contiguous runs -> scatter packed
// (src | dstLocal<<20).  Runs ~21 edges (84B) => low write amplification.
__global__ void __launch_bounds__(256) k_partition(
        const int* __restrict__ src, const int* __restrict__ dst,
        int* __restrict__ bcur, unsigned int* __restrict__ ebuf, int E) {
    __shared__ int hist[NB];
    __shared__ int lcur[NB];
    int e0 = blockIdx.x * EPB;
    int e1 = min(e0 + EPB, E);
    for (int t = threadIdx.x; t < NB; t += 256) { hist[t] = 0; lcur[t] = 0; }
    __syncthreads();
    for (int e = e0 + threadIdx.x; e < e1; e += 256)
        atomicAdd(&hist[dst[e] >> BSH], 1);
    __syncthreads();
    for (int t = threadIdx.x; t < NB; t += 256) {
        int c = hist[t];
        hist[t] = c ? atomicAdd(&bcur[t], c) : 0;
    }
    __syncthreads();
    for (int e = e0 + threadIdx.x; e < e1; e += 256) {
        int d = dst[e];
        int b = d >> BSH;
        int pos = hist[b] + atomicAdd(&lcur[b], 1);
        ebuf[pos] = (unsigned)src[e] | ((unsigned)(d & (NPB - 1)) << 20);
    }
}

// per-bucket counting sort by dstLocal (thread t owns local node t):
// builds col (node-sorted src), rowptr, dinv.
__global__ void __launch_bounds__(256) k_csr(
        const int* __restrict__ bbase, const unsigned int* __restrict__ ebuf,
        int* __restrict__ col, int* __restrict__ rowptr, float* __restrict__ dinv,
        int N) {
    __shared__ int hist[NPB];
    __shared__ int base[NPB];
    __shared__ int lcur[NPB];
    __shared__ int wsum[4];
    int b = blockIdx.x;
    int tid = threadIdx.x;
    int beg = bbase[b], end = bbase[b + 1];
    hist[tid] = 0; lcur[tid] = 0;
    __syncthreads();
    for (int j = beg + tid; j < end; j += 256)
        atomicAdd(&hist[ebuf[j] >> 20], 1);
    __syncthreads();
    int lane = tid & 63, w = tid >> 6;
    int v = hist[tid];
    int incl = v;
#pragma unroll
    for (int off = 1; off < 64; off <<= 1) {
        int u = __shfl_up(incl, off);
        if (lane >= off) incl += u;
    }
    if (lane == 63) wsum[w] = incl;
    __syncthreads();
    int woff = 0;
#pragma unroll
    for (int k = 0; k < 4; k++) woff += (k < w) ? wsum[k] : 0;
    int excl = incl - v + woff;
    base[tid] = excl;
    int node = (b << BSH) + tid;
    if (node < N) {
        rowptr[node] = beg + excl;
        dinv[node] = rsqrtf((float)(v + 1));  // +1 self loop
    }
    if (b == NB - 1 && tid == 0) rowptr[N] = NE;
    __syncthreads();
    for (int j = beg + tid; j < end; j += 256) {
        unsigned pe = ebuf[j];
        int dl = pe >> 20;
        int pos = beg + base[dl] + atomicAdd(&lcur[dl], 1);
        col[pos] = (int)(pe & 0xFFFFF);
    }
}

// xs[i,f] = x[i,f] * dinv[i]
__global__ void k_scale(const float* __restrict__ x, const float* __restrict__ dinv,
                        float* __restrict__ xs, int N4) {
    int i4 = blockIdx.x * blockDim.x + threadIdx.x;
    if (i4 >= N4) return;
    float di = dinv[i4 >> 2];
    float4 v = ((const float4*)x)[i4];
    v.x *= di; v.y *= di; v.z *= di; v.w *= di;
    ((float4*)xs)[i4] = v;
}

// Layer-1 fused: one wave per node. 4 lanes/edge, float4 gather, unroll x2 so
// both col loads + both gathers are in flight together. agg16 -> @W1 (+b1,
// relu) -> @W2 -> *dinv -> g2[4] (padded).
__global__ void __launch_bounds__(256) k_l1(
        const int* __restrict__ rowptr, const int* __restrict__ col,
        const float* __restrict__ xs, const float* __restrict__ dinv,
        const float* __restrict__ W1, const float* __restrict__ b1,
        const float* __restrict__ W2, float* __restrict__ g2, int N) {
    __shared__ float W1s[16 * 32];
    __shared__ float W2s[96];
    __shared__ float b1s[32];
    for (int t = threadIdx.x; t < 512; t += 256) W1s[t] = W1[t];
    if (threadIdx.x < 96) W2s[threadIdx.x] = W2[threadIdx.x];
    if (threadIdx.x < 32) b1s[threadIdx.x] = b1[threadIdx.x];
    __syncthreads();
    int wid = (int)((blockIdx.x * 256 + threadIdx.x) >> 6);
    if (wid >= N) return;  // wave-uniform
    int lane = threadIdx.x & 63;
    int r = lane >> 2, c = lane & 3;  // edge slot 0..15, float4 chunk 0..3
    int beg = rowptr[wid], end = rowptr[wid + 1];
    const float4* xs4 = (const float4*)xs;
    float4 a4 = make_float4(0.f, 0.f, 0.f, 0.f);
    int j = beg + r;
    while (j + 16 < end) {     // 2 edges per lane in flight
        int s0 = col[j];
        int s1 = col[j + 16];
        float4 v0 = xs4[(size_t)s0 * 4 + c];
        float4 v1 = xs4[(size_t)s1 * 4 + c];
        a4.x += v0.x; a4.y += v0.y; a4.z += v0.z; a4.w += v0.w;
        a4.x += v1.x; a4.y += v1.y; a4.z += v1.z; a4.w += v1.w;
        j += 32;
    }
    if (j < end) {
        int s = col[j];
        float4 v = xs4[(size_t)s * 4 + c];
        a4.x += v.x; a4.y += v.y; a4.z += v.z; a4.w += v.w;
    }
    // fold 16 edge slots -> lanes 0..3 (per-component shfl)
#pragma unroll
    for (int off = 32; off >= 4; off >>= 1) {
        a4.x += __shfl_down(a4.x, off);
        a4.y += __shfl_down(a4.y, off);
        a4.z += __shfl_down(a4.z, off);
        a4.w += __shfl_down(a4.w, off);
    }
    if (lane < 4) {  // self term
        float4 v = xs4[(size_t)wid * 4 + lane];
        a4.x += v.x; a4.y += v.y; a4.z += v.z; a4.w += v.w;
    }
    float di = dinv[wid];
    // broadcast agg[0..15]: feature k lives in component (k&3) of lane (k>>2)
    float o0 = 0.f, o1 = 0.f;
    int f = lane & 15;
#pragma unroll
    for (int k = 0; k < 16; k++) {
        float comp = (k & 3) == 0 ? a4.x : (k & 3) == 1 ? a4.y : (k & 3) == 2 ? a4.z : a4.w;
        float a = __shfl(comp, k >> 2);
        o0 = fmaf(a, W1s[k * 32 + 2 * f + 0], o0);
        o1 = fmaf(a, W1s[k * 32 + 2 * f + 1], o1);
    }
    float z0 = fmaxf(fmaf(di, o0, b1s[2 * f + 0]), 0.f);
    float z1 = fmaxf(fmaf(di, o1, b1s[2 * f + 1]), 0.f);
    float p0 = fmaf(z0, W2s[(2 * f) * 3 + 0], z1 * W2s[(2 * f + 1) * 3 + 0]);
    float p1 = fmaf(z0, W2s[(2 * f) * 3 + 1], z1 * W2s[(2 * f + 1) * 3 + 1]);
    float p2 = fmaf(z0, W2s[(2 * f) * 3 + 2], z1 * W2s[(2 * f + 1) * 3 + 2]);
#pragma unroll
    for (int off = 8; off >= 1; off >>= 1) {  // sum lanes 0..15 into lane 0
        p0 += __shfl_down(p0, off);
        p1 += __shfl_down(p1, off);
        p2 += __shfl_down(p2, off);
    }
    if (lane == 0) {
        float4 o;
        o.x = p0 * di; o.y = p1 * di; o.z = p2 * di; o.w = 0.f;
        ((float4*)g2)[wid] = o;   // padded stride-4 row
    }
}

// Layer-2 fused: HALF-wave (32 lanes) per node — deg~32 so full wave wasted
// half its lanes. Width-32 shuffles keep the two halves independent.
__global__ void __launch_bounds__(256) k_l2(
        const int* __restrict__ rowptr, const int* __restrict__ col,
        const float* __restrict__ g2, const float* __restrict__ dinv,
        const float* __restrict__ b2, float* __restrict__ out, int N) {
    int wid = (int)((blockIdx.x * 256 + threadIdx.x) >> 5);  // node per half-wave
    if (wid >= N) return;
    int l = threadIdx.x & 31;
    int beg = rowptr[wid], end = rowptr[wid + 1];
    const float4* g24 = (const float4*)g2;
    float a0 = 0.f, a1 = 0.f, a2 = 0.f;
    for (int j = beg + l; j < end; j += 32) {
        float4 v = g24[col[j]];
        a0 += v.x; a1 += v.y; a2 += v.z;
    }
#pragma unroll
    for (int off = 16; off >= 1; off >>= 1) {
        a0 += __shfl_down(a0, off, 32);
        a1 += __shfl_down(a1, off, 32);
        a2 += __shfl_down(a2, off, 32);
    }
    if (l == 0) {
        float di = dinv[wid];
        float4 self = g24[wid];
        float v0 = fmaf(di, a0 + self.x, b2[0]);
        float v1 = fmaf(di, a1 + self.y, b2[1]);
        float v2 = fmaf(di, a2 + self.z, b2[2]);
        float m = fmaxf(v0, fmaxf(v1, v2));
        float lse = m + logf(expf(v0 - m) + expf(v1 - m) + expf(v2 - m));
        out[(size_t)wid * 3 + 0] = v0 - lse;
        out[(size_t)wid * 3 + 1] = v1 - lse;
        out[(size_t)wid * 3 + 2] = v2 - lse;
    }
}

// ---------------- launch ----------------

extern "C" void kernel_launch(void* const* d_in, const int* in_sizes, int n_in,
                              void* d_out, int out_size, void* d_ws, size_t ws_size,
                              hipStream_t stream) {
    const float* x  = (const float*)d_in[0];
    const int*   ei = (const int*)d_in[1];   // [2, E] int32
    const float* W1 = (const float*)d_in[2];
    const float* b1 = (const float*)d_in[3];
    const float* W2 = (const float*)d_in[4];
    const float* b2 = (const float*)d_in[5];
    float* out = (float*)d_out;

    const int* src = ei;
    const int* dst = ei + NE;

    // ws (4B units): ebuf[NE] (xs[N*16] aliases it after k_csr)
    //              | col[NE] | g2[N*4] | dinv[N] | rowptr[N+1] | bcnt | bbase | bcur
    unsigned int* ebuf = (unsigned int*)d_ws;
    float* xs   = (float*)d_ws;              // alias: ebuf dead after k_csr
    int*   col  = (int*)(ebuf + (size_t)NE);
    float* g2   = (float*)(col + (size_t)NE);
    float* dinv = g2 + (size_t)NN * 4;
    int*   rowptr = (int*)(dinv + NN);
    int*   bcnt = rowptr + NN + 1;
    int*   bbase = bcnt + NB;
    int*   bcur  = bbase + NB + 1;

    (void)hipMemsetAsync(bcnt, 0, (size_t)NB * 4, stream);

    const int B = 256;
    int gbP = (NE + EPB - 1) / EPB;
    int gbS = (NN * 4 + B - 1) / B;
    int gbW1 = (NN * 64 + B - 1) / B;  // wave per node
    int gbW2 = (NN * 32 + B - 1) / B;  // half-wave per node

    k_count<<<512, B, 0, stream>>>((const int4*)dst, bcnt, NE / 4);
    k_scanb<<<1, 1024, 0, stream>>>(bcnt, bbase, bcur);
    k_partition<<<gbP, B, 0, stream>>>(src, dst, bcur, ebuf, NE);
    k_csr<<<NB, B, 0, stream>>>(bbase, ebuf, col, rowptr, dinv, NN);
    k_scale<<<gbS, B, 0, stream>>>(x, dinv, xs, NN * 4);
    k_l1<<<gbW1, B, 0, stream>>>(rowptr, col, xs, dinv, W1, b1, W2, g2, NN);
    k_l2<<<gbW2, B, 0, stream>>>(rowptr, col, g2, dinv, b2, out, NN);
}